// Round 7
// baseline (1470.682 us; speedup 1.0000x reference)
//
#include <hip/hip_runtime.h>

// DecoderWithAttention: B=16, T=32, F=8, S_ENC=256, H=512, L=2.
// R13: single kernel, 3 syncs/step (was 4), overlap folds, wave0-only polls.
//  - hidP computed LOCALLY by every block (whid full read, L2-shared/XCD):
//    kills the hidP sync entirely.
//  - Remaining syncs: att partials (flag+payload), h0 LL gather, h1 LL gather.
//  - Overlaps: Whh0@h0 during att wait; Whh1@h1 during h0 wait; out-projection
//    weighted/xin partial during h1 wait.
//  - h0/h1 gathers polled by wave 0 only (4 chunks/lane) -> 4x less uncached
//    poll traffic; other waves park at s_barrier.
//  - Internal prologue (pack -> agent flush -> encp self-slice) as R10.

namespace {
constexpr int NTHR = 256, NBLK = 256;

// ws layout (float/u32 units). memset covers [0, 147456) bytes.
constexpr int OFF_FLG     = 0;        // [16][16][16] u32 att flags (16B/wave)
// u32 8192 = grid counter (inside old hidpLL region, memset'd, unused otherwise)
constexpr int OFF_H0LL    = 20480;    // [16][256] u64 LL chunks
constexpr int OFF_H1LL    = 28672;    // [16][256] u64
constexpr int OFF_ATTP    = 36864;    // [16][16][514] f32 payload (flag-gated)
constexpr int OFF_AEH     = 168448;   // [512][256] u32 attn_W[:,512:]
constexpr int OFF_WHID    = OFF_AEH + 131072;    // [512][256] u32
constexpr int OFF_WIH0    = OFF_WHID + 131072;   // [1536][260] u32
constexpr int OFF_WHH0    = OFF_WIH0 + 399360;   // [1536][256] u32
constexpr int OFF_WIH1    = OFF_WHH0 + 393216;
constexpr int OFF_WHH1    = OFF_WIH1 + 393216;
constexpr int OFF_ENCP    = OFF_WHH1 + 393216;   // [4096][256] u32

// main-loop LDS (floats). P2 prologue staging overlays [0..8192).
constexpr int L_H1   = 0;      // [256] u32 h1(t) f16x2
constexpr int L_H0   = 256;    // [256] u32 h0(t) f16x2
constexpr int L_HIDP = 512;    // [512] f32
constexpr int L_ES   = 1024;   // [256] f32 (es[16] in B; L[16] + out[8] later)
constexpr int L_HX   = 1280;   // [264] u32: xin(4)|weighted(256)|pad(4)
constexpr int L_AX   = 1544;   // [96]
constexpr int L_AH   = 1640;   // [96]  Whh0@h0 + bhh0 (att-wait fold)
constexpr int L_AH1  = 1736;   // [96]  Whh1@h1 + bhh1 (h0-wait fold)
constexpr int L_HS   = 1832;   // [32]
constexpr int L_OWP  = 1864;   // [8] out partial (h1-wait fold)
constexpr int L_BIH0 = 1872, L_BHH0 = 1968, L_BIH1 = 2064, L_BHH1 = 2160;  // [96]
constexpr int L_VW   = 2256;   // [512]
constexpr int L_XIN  = 2768;   // [8]
constexpr int LDS_FLOATS = 8192;
}  // namespace

typedef _Float16 h2 __attribute__((ext_vector_type(2)));
union U32H { unsigned u; h2 h; };

__device__ __forceinline__ float dot2(unsigned a, unsigned b, float acc) {
    U32H ua, ub; ua.u = a; ub.u = b;
#if __has_builtin(__builtin_amdgcn_fdot2)
    return __builtin_amdgcn_fdot2(ua.h, ub.h, acc, false);
#else
    return acc + (float)ua.h.x * (float)ub.h.x + (float)ua.h.y * (float)ub.h.y;
#endif
}
__device__ __forceinline__ unsigned packh2(float a, float b) {
    U32H u; u.h = h2{(_Float16)a, (_Float16)b}; return u.u;
}
__device__ __forceinline__ float fsig(float x) { return 1.0f / (1.0f + __expf(-x)); }
__device__ __forceinline__ float ftanhf(float x) {
    float e = __expf(2.0f * x);
    return 1.0f - 2.0f / (e + 1.0f);
}
__device__ __forceinline__ float cload(const float* p) {
    return __hip_atomic_load(p, __ATOMIC_RELAXED, __HIP_MEMORY_SCOPE_SYSTEM);
}
__device__ __forceinline__ void cstore(float* p, float v) {
    __hip_atomic_store(p, v, __ATOMIC_RELAXED, __HIP_MEMORY_SCOPE_SYSTEM);
}
__device__ __forceinline__ unsigned ucload(const unsigned* p) {
    return __hip_atomic_load(p, __ATOMIC_RELAXED, __HIP_MEMORY_SCOPE_SYSTEM);
}

// LL 8B chunk ops (single-instruction system-scope store / load-returns-payload)
__device__ __forceinline__ void ll_store(unsigned long long* p, unsigned payload,
                                         unsigned stamp) {
    unsigned long long v = (unsigned long long)payload | ((unsigned long long)stamp << 32);
    asm volatile("global_store_dwordx2 %0, %1, off sc0 sc1" :: "v"(p), "v"(v) : "memory");
}
__device__ __forceinline__ unsigned long long ll_load(const unsigned long long* p) {
    unsigned long long v;
    asm volatile("global_load_dwordx2 %0, %1, off sc0 sc1\n\ts_waitcnt vmcnt(0)"
                 : "=v"(v) : "v"(p) : "memory");
    return v;
}
__device__ __forceinline__ unsigned ll_poll(const unsigned long long* p, unsigned stamp) {
    for (;;) {
        unsigned long long v = ll_load(p);
        if ((unsigned)(v >> 32) == stamp) return (unsigned)v;
        __builtin_amdgcn_s_sleep(1);
    }
}
__device__ __forceinline__ void flag_store(unsigned* p, unsigned v) {
    asm volatile("global_store_dword %0, %1, off sc0 sc1" :: "v"(p), "v"(v) : "memory");
}

// Prologue barrier: one agent-scope wbl2 (release) / inv (acquire) per block.
__device__ __forceinline__ void bar_sync_flush(unsigned* cnt, unsigned target) {
    __syncthreads();
    if (threadIdx.x == 0) {
        __builtin_amdgcn_fence(__ATOMIC_RELEASE, "agent");
        __hip_atomic_fetch_add(cnt, 1u, __ATOMIC_RELAXED, __HIP_MEMORY_SCOPE_SYSTEM);
        while (__hip_atomic_load(cnt, __ATOMIC_RELAXED, __HIP_MEMORY_SCOPE_SYSTEM) < target)
            __builtin_amdgcn_s_sleep(8);
        __builtin_amdgcn_fence(__ATOMIC_ACQUIRE, "agent");
    }
    __syncthreads();
}

__global__ __launch_bounds__(NTHR) void decoder_kernel(
    const float* __restrict__ target, const float* __restrict__ hidden0,
    const float* __restrict__ enc, const float* __restrict__ attn_W,
    const float* __restrict__ attn_b, const float* __restrict__ v_w,
    const float* __restrict__ Wih0, const float* __restrict__ Whh0,
    const float* __restrict__ bih0, const float* __restrict__ bhh0,
    const float* __restrict__ Wih1, const float* __restrict__ Whh1,
    const float* __restrict__ bih1, const float* __restrict__ bhh1,
    const float* __restrict__ outW, const float* __restrict__ outBias,
    float* __restrict__ out, float* __restrict__ ws) {
    const int tid = threadIdx.x, bid = blockIdx.x;
    const int b = bid >> 4, s = bid & 15;

    unsigned* flg = (unsigned*)ws + OFF_FLG;
    unsigned* gridCnt = (unsigned*)ws + 8192;
    unsigned long long* h0LL = (unsigned long long*)(ws + OFF_H0LL);
    unsigned long long* h1LL = (unsigned long long*)(ws + OFF_H1LL);
    float* attP = ws + OFF_ATTP;
    unsigned* aehU  = (unsigned*)(ws + OFF_AEH);
    unsigned* whidU = (unsigned*)(ws + OFF_WHID);
    unsigned* wih0U = (unsigned*)(ws + OFF_WIH0);
    unsigned* whh0U = (unsigned*)(ws + OFF_WHH0);
    unsigned* wih1U = (unsigned*)(ws + OFF_WIH1);
    unsigned* whh1U = (unsigned*)(ws + OFF_WHH1);
    unsigned* encpU = (unsigned*)(ws + OFF_ENCP);

    __shared__ __align__(16) float lds[LDS_FLOATS];
    unsigned* ldsU = (unsigned*)lds;
    const int gtid = bid * NTHR + tid;

    // ===================== P1: f16 pack (plain stores) ========================
    for (int i = gtid; i < 131072; i += NBLK * NTHR) {
        const int jr = i >> 8, p = i & 255;
        aehU[i]  = packh2(attn_W[jr * 1024 + 512 + 2 * p], attn_W[jr * 1024 + 513 + 2 * p]);
        whidU[i] = packh2(attn_W[jr * 1024 + 2 * p], attn_W[jr * 1024 + 1 + 2 * p]);
    }
    for (int i = gtid; i < 399360; i += NBLK * NTHR)
        wih0U[i] = packh2(Wih0[2 * i], Wih0[2 * i + 1]);
    for (int i = gtid; i < 393216; i += NBLK * NTHR) {
        whh0U[i] = packh2(Whh0[2 * i], Whh0[2 * i + 1]);
        wih1U[i] = packh2(Wih1[2 * i], Wih1[2 * i + 1]);
        whh1U[i] = packh2(Whh1[2 * i], Whh1[2 * i + 1]);
    }
    bar_sync_flush(gridCnt, NBLK);  // one wbl2/inv per block

    // ===================== P2: enc_proj for own (b, 16 s) — self-read only ====
    {
        for (int i = 0; i < 32; ++i) {
            const int idx = tid + i * 256;
            lds[idx] = enc[(b * 256 + s * 16) * 512 + idx];  // 16 s x 512
        }
        __syncthreads();
        float a0[16], a1[16];
        const float bb0 = attn_b[2 * tid], bb1 = attn_b[2 * tid + 1];
#pragma unroll
        for (int sl = 0; sl < 16; ++sl) { a0[sl] = bb0; a1[sl] = bb1; }
        const unsigned* w0 = &aehU[(2 * tid) * 256];
        const unsigned* w1 = &aehU[(2 * tid + 1) * 256];
        for (int p = 0; p < 256; ++p) {
            const unsigned ww0 = w0[p], ww1 = w1[p];
#pragma unroll
            for (int sl = 0; sl < 16; ++sl) {
                const unsigned epk = packh2(lds[sl * 512 + 2 * p], lds[sl * 512 + 2 * p + 1]);
                a0[sl] = dot2(epk, ww0, a0[sl]);
                a1[sl] = dot2(epk, ww1, a1[sl]);
            }
        }
        for (int sl = 0; sl < 16; ++sl)  // self-read only (plain stores)
            encpU[(b * 256 + s * 16 + sl) * 256 + tid] = packh2(a0[sl], a1[sl]);
        __syncthreads();
    }

    // ===================== P3: init LDS state =================================
    if (tid < 96) {
        const int grow = (tid >> 5) * 512 + s * 32 + (tid & 31);
        lds[L_BIH0 + tid] = bih0[grow]; lds[L_BHH0 + tid] = bhh0[grow];
        lds[L_BIH1 + tid] = bih1[grow]; lds[L_BHH1 + tid] = bhh1[grow];
    }
    lds[L_VW + tid] = v_w[tid];
    lds[L_VW + 256 + tid] = v_w[256 + tid];
    ldsU[L_H0 + tid] = packh2(hidden0[b * 512 + 2 * tid], hidden0[b * 512 + 2 * tid + 1]);
    ldsU[L_H1 + tid] = packh2(hidden0[8192 + b * 512 + 2 * tid],
                              hidden0[8192 + b * 512 + 2 * tid + 1]);
    if (tid < 8) lds[L_XIN + tid] = target[b * 256 + tid];
    if (tid < 4) ldsU[L_HX + 260 + tid] = 0u;  // permanent zero tail pad
    __syncthreads();

    for (int t = 0; t < 32; ++t) {
        const unsigned tgt = (unsigned)(t + 1);

        // ---- A: hidP FULL, locally (2 rows/thread; whid L2-shared) ----
        {
            const uint4* h1v = (const uint4*)&ldsU[L_H1];
#pragma unroll
            for (int half = 0; half < 2; ++half) {
                const int row = half * 256 + tid;
                const uint4* w = (const uint4*)&whidU[row * 256];
                float a0 = 0.f, a1 = 0.f;
#pragma unroll 8
                for (int k = 0; k < 64; k += 2) {
                    const uint4 wv0 = w[k], hv0 = h1v[k];
                    a0 = dot2(hv0.x, wv0.x, a0); a0 = dot2(hv0.y, wv0.y, a0);
                    a0 = dot2(hv0.z, wv0.z, a0); a0 = dot2(hv0.w, wv0.w, a0);
                    const uint4 wv1 = w[k + 1], hv1 = h1v[k + 1];
                    a1 = dot2(hv1.x, wv1.x, a1); a1 = dot2(hv1.y, wv1.y, a1);
                    a1 = dot2(hv1.z, wv1.z, a1); a1 = dot2(hv1.w, wv1.w, a1);
                }
                lds[L_HIDP + row] = a0 + a1;
            }
        }
        __syncthreads();

        // ---- B: energy own 16 s + exp + att payload + per-wave flag ----
        {
            const int sloc = tid >> 4, sub = tid & 15;
            const unsigned* ep = &encpU[(b * 256 + s * 16 + sloc) * 256];
            float acc = 0.f;
#pragma unroll 4
            for (int k2 = 0; k2 < 16; ++k2) {
                const int p = k2 * 16 + sub;
                U32H u; u.u = ep[p];
                acc += lds[L_VW + 2 * p] * ftanhf((float)u.h.x + lds[L_HIDP + 2 * p]);
                acc += lds[L_VW + 2 * p + 1] * ftanhf((float)u.h.y + lds[L_HIDP + 2 * p + 1]);
            }
            acc += __shfl_down(acc, 8, 16); acc += __shfl_down(acc, 4, 16);
            acc += __shfl_down(acc, 2, 16); acc += __shfl_down(acc, 1, 16);
            if (sub == 0) lds[L_ES + sloc] = __expf(acc);  // |score|<=~20: fp32-safe
        }
        __syncthreads();
        {
            float wp0 = 0.f, wp1 = 0.f;
            const float2* er = (const float2*)&enc[(b * 256 + s * 16) * 512];
#pragma unroll
            for (int sl = 0; sl < 16; ++sl) {
                const float2 e = er[sl * 256 + tid];
                const float es = lds[L_ES + sl];
                wp0 += es * e.x; wp1 += es * e.y;
            }
            cstore(&attP[(b * 16 + s) * 514 + 2 * tid], wp0);
            cstore(&attP[(b * 16 + s) * 514 + 2 * tid + 1], wp1);
            if (tid == 0) {
                float l = 0.f;
#pragma unroll
                for (int i = 0; i < 16; ++i) l += lds[L_ES + i];
                cstore(&attP[(b * 16 + s) * 514 + 512], l);
            }
        }
        asm volatile("s_waitcnt vmcnt(0)" ::: "memory");
        if ((tid & 63) == 0)
            flag_store(&flg[(b * 16 + s) * 16 + (tid >> 6) * 4], tgt);

        // ---- fold: ah0 = Whh0@h0 + bhh0 (overlaps att wait) ----
        if (tid < 192) {
            const int u = tid >> 1, sub = tid & 1;
            const int gh = u >> 5, r = u & 31;
            const int grow = gh * 512 + s * 32 + r;
            const uint4* wh = (const uint4*)&whh0U[grow * 256 + sub * 128];
            const uint4* hp = (const uint4*)&ldsU[L_H0 + sub * 128];
            float ah = 0.f;
#pragma unroll 8
            for (int k4 = 0; k4 < 32; ++k4) {
                const uint4 hv = hp[k4], wv = wh[k4];
                ah = dot2(hv.x, wv.x, ah); ah = dot2(hv.y, wv.y, ah);
                ah = dot2(hv.z, wv.z, ah); ah = dot2(hv.w, wv.w, ah);
            }
            ah += __shfl_down(ah, 1, 2);
            if (sub == 0) lds[L_AH + u] = ah + lds[L_BHH0 + u];
        }

        // ---- att gather: 64 flag polls -> bulk payload ----
        if (tid < 64) {
            const unsigned* fp = &flg[(b * 16 + (tid >> 2)) * 16 + (tid & 3) * 4];
            while (ucload(fp) < tgt) __builtin_amdgcn_s_sleep(1);
        }
        __syncthreads();
        __builtin_amdgcn_fence(__ATOMIC_ACQUIRE, "workgroup");
        {
            float w0 = 0.f, w1 = 0.f;
            for (int sp = 0; sp < 16; ++sp) {
                w0 += cload(&attP[(b * 16 + sp) * 514 + 2 * tid]);
                w1 += cload(&attP[(b * 16 + sp) * 514 + 2 * tid + 1]);
            }
            if (tid < 16) lds[L_ES + tid] = cload(&attP[(b * 16 + tid) * 514 + 512]);
            __syncthreads();
            float L = 0.f;
#pragma unroll
            for (int i = 0; i < 16; ++i) L += lds[L_ES + i];
            const float inv = 1.f / L;
            ldsU[L_HX + 4 + tid] = packh2(w0 * inv, w1 * inv);
            if (tid < 4)
                ldsU[L_HX + tid] = packh2(lds[L_XIN + 2 * tid], lds[L_XIN + 2 * tid + 1]);
        }
        __syncthreads();

        // ---- C: GRU0 ax (own rows) + gates -> h0 slice LL ----
        if (tid < 192) {
            const int u = tid >> 1, sub = tid & 1;
            const int gh = u >> 5, r = u & 31;
            const int grow = gh * 512 + s * 32 + r;
            const uint4* wx = (const uint4*)&wih0U[grow * 260 + sub * 132];
            const uint4* xp = (const uint4*)&ldsU[L_HX + sub * 132];
            float ax = 0.f;
#pragma unroll 11
            for (int k4 = 0; k4 < 33; ++k4) {
                const uint4 xv = xp[k4], wv = wx[k4];
                ax = dot2(xv.x, wv.x, ax); ax = dot2(xv.y, wv.y, ax);
                ax = dot2(xv.z, wv.z, ax); ax = dot2(xv.w, wv.w, ax);
            }
            ax += __shfl_down(ax, 1, 2);
            if (sub == 0) lds[L_AX + u] = ax + lds[L_BIH0 + u];
        }
        __syncthreads();
        if (tid < 32) {
            const int r = tid;
            const float rg = fsig(lds[L_AX + r] + lds[L_AH + r]);
            const float z = fsig(lds[L_AX + 32 + r] + lds[L_AH + 32 + r]);
            const float n = ftanhf(lds[L_AX + 64 + r] + rg * lds[L_AH + 64 + r]);
            U32H u; u.u = ldsU[L_H0 + s * 16 + (r >> 1)];
            const float hold = (r & 1) ? (float)u.h.y : (float)u.h.x;
            lds[L_HS + r] = (1.f - z) * n + z * hold;
        }
        __syncthreads();
        if (tid < 16)
            ll_store(&h0LL[b * 256 + s * 16 + tid],
                     packh2(lds[L_HS + 2 * tid], lds[L_HS + 2 * tid + 1]), tgt);

        // ---- fold: ah1 = Whh1@h1 + bhh1 (overlaps h0 wait) ----
        if (tid < 192) {
            const int u = tid >> 1, sub = tid & 1;
            const int gh = u >> 5, r = u & 31;
            const int grow = gh * 512 + s * 32 + r;
            const uint4* wh = (const uint4*)&whh1U[grow * 256 + sub * 128];
            const uint4* hp = (const uint4*)&ldsU[L_H1 + sub * 128];
            float ah = 0.f;
#pragma unroll 8
            for (int k4 = 0; k4 < 32; ++k4) {
                const uint4 hv = hp[k4], wv = wh[k4];
                ah = dot2(hv.x, wv.x, ah); ah = dot2(hv.y, wv.y, ah);
                ah = dot2(hv.z, wv.z, ah); ah = dot2(hv.w, wv.w, ah);
            }
            ah += __shfl_down(ah, 1, 2);
            if (sub == 0) lds[L_AH1 + u] = ah + lds[L_BHH1 + u];
        }

        // ---- h0 gather: wave 0 polls 4 chunks/lane ----
        if (tid < 64) {
#pragma unroll
            for (int i = 0; i < 4; ++i) {
                const int idx = tid * 4 + i;
                ldsU[L_H0 + idx] = ll_poll(&h0LL[b * 256 + idx], tgt);
            }
        }
        __syncthreads();

        // ---- D: GRU1 ax (own rows, x=h0new) + gates -> h1 slice LL ----
        if (tid < 192) {
            const int u = tid >> 1, sub = tid & 1;
            const int gh = u >> 5, r = u & 31;
            const int grow = gh * 512 + s * 32 + r;
            const uint4* wx = (const uint4*)&wih1U[grow * 256 + sub * 128];
            const uint4* xp = (const uint4*)&ldsU[L_H0 + sub * 128];
            float ax = 0.f;
#pragma unroll 8
            for (int k4 = 0; k4 < 32; ++k4) {
                const uint4 xv = xp[k4], wv = wx[k4];
                ax = dot2(xv.x, wv.x, ax); ax = dot2(xv.y, wv.y, ax);
                ax = dot2(xv.z, wv.z, ax); ax = dot2(xv.w, wv.w, ax);
            }
            ax += __shfl_down(ax, 1, 2);
            if (sub == 0) lds[L_AX + u] = ax + lds[L_BIH1 + u];
        }
        __syncthreads();
        if (tid < 32) {
            const int r = tid;
            const float rg = fsig(lds[L_AX + r] + lds[L_AH1 + r]);
            const float z = fsig(lds[L_AX + 32 + r] + lds[L_AH1 + 32 + r]);
            const float n = ftanhf(lds[L_AX + 64 + r] + rg * lds[L_AH1 + 64 + r]);
            U32H u; u.u = ldsU[L_H1 + s * 16 + (r >> 1)];
            const float hold = (r & 1) ? (float)u.h.y : (float)u.h.x;
            lds[L_HS + r] = (1.f - z) * n + z * hold;
        }
        __syncthreads();
        if (tid < 16)
            ll_store(&h1LL[b * 256 + s * 16 + tid],
                     packh2(lds[L_HS + 2 * tid], lds[L_HS + 2 * tid + 1]), tgt);

        // ---- fold: out weighted/xin partial (overlaps h1 wait) ----
        {
            const int f = tid >> 5, l = tid & 31;
            const float* ow = &outW[f * 1032 + 512];
            float acc = 0.f;
#pragma unroll
            for (int i = 0; i < 8; ++i) {
                const int k2 = i * 32 + l;
                U32H u; u.u = ldsU[L_HX + 4 + k2];
                acc += ow[2 * k2] * (float)u.h.x + ow[2 * k2 + 1] * (float)u.h.y;
            }
            if (l < 8) acc += outW[f * 1032 + 1024 + l] * lds[L_XIN + l];
            acc += __shfl_down(acc, 16, 32); acc += __shfl_down(acc, 8, 32);
            acc += __shfl_down(acc, 4, 32); acc += __shfl_down(acc, 2, 32);
            acc += __shfl_down(acc, 1, 32);
            if (l == 0) lds[L_OWP + f] = acc;
        }

        // ---- h1 gather: wave 0 polls 4 chunks/lane ----
        if (tid < 64) {
#pragma unroll
            for (int i = 0; i < 4; ++i) {
                const int idx = tid * 4 + i;
                ldsU[L_H1 + idx] = ll_poll(&h1LL[b * 256 + idx], tgt);
            }
        }
        __syncthreads();

        // ---- E: out final (h1 part) + relu + xin update ----
        {
            const int f = tid >> 5, l = tid & 31;
            const float* ow = &outW[f * 1032];
            float acc = 0.f;
#pragma unroll
            for (int i = 0; i < 8; ++i) {
                const int k2 = i * 32 + l;
                U32H u; u.u = ldsU[L_H1 + k2];
                acc += ow[2 * k2] * (float)u.h.x + ow[2 * k2 + 1] * (float)u.h.y;
            }
            acc += __shfl_down(acc, 16, 32); acc += __shfl_down(acc, 8, 32);
            acc += __shfl_down(acc, 4, 32); acc += __shfl_down(acc, 2, 32);
            acc += __shfl_down(acc, 1, 32);
            if (l == 0) {
                const float o = fmaxf(acc + lds[L_OWP + f] + outBias[f], 0.f);
                lds[L_ES + f] = o;
                if (s == 0) out[b * 256 + t * 8 + f] = o;
            }
        }
        __syncthreads();
        if (tid < 8) lds[L_XIN + tid] = lds[L_ES + tid];
        __syncthreads();
    }
}

extern "C" void kernel_launch(void* const* d_in, const int* in_sizes, int n_in,
                              void* d_out, int out_size, void* d_ws, size_t ws_size,
                              hipStream_t stream) {
    (void)in_sizes; (void)n_in; (void)out_size; (void)ws_size;
    hipMemsetAsync(d_ws, 0, 147456, stream);  // flags + LL stamps + grid counter
    decoder_kernel<<<NBLK, NTHR, 0, stream>>>(
        (const float*)d_in[0], (const float*)d_in[1], (const float*)d_in[2],
        (const float*)d_in[3], (const float*)d_in[4], (const float*)d_in[5],
        (const float*)d_in[6], (const float*)d_in[7], (const float*)d_in[8],
        (const float*)d_in[9], (const float*)d_in[10], (const float*)d_in[11],
        (const float*)d_in[12], (const float*)d_in[13], (const float*)d_in[14],
        (const float*)d_in[15], (float*)d_out, (float*)d_ws);
}

// Round 8
// 1433.025 us; speedup vs baseline: 1.0263x; 1.0263x over previous
//
#include <hip/hip_runtime.h>

// DecoderWithAttention: B=16, T=32, F=8, S_ENC=256, H=512, L=2.
// R14 = R10 (proven 834us: 256 blocks, tag+payload sync, parallel polls,
// internal prologue) with the hidP sync MERGED into the h1 sync:
//  - block s ships hidP partials (whid[:, s*32:+32] @ h1slice, 512 f32,
//    16k MACs from a 32KB transposed whidT slice) in the h1 payload.
//    4 syncs/step -> 3. No redundant streaming (R13's mistake).
//  - t=0: one-time full local hidP (h1(0) is local after init).
//  - out projection: h1-part at next-step top; weighted/xin part folded
//    after tag3 store. ah0/ah1 folds between tag store and poll.
//  - polls stay one-per-thread parallel (R13's serial polls regressed).

namespace {
constexpr int NTHR = 256, NBLK = 256;

// ws float/u32 offsets. memset covers [0, 36864) bytes.
constexpr int OFF_TAG   = 0;          // [256][32] u32: tags[bid*32 + phase]
constexpr int OFF_GRID  = 8192;       // u32 grid counter (prologue)
constexpr int OFF_ATTP  = 8448;       // [256][516] f32 (512 wp + L @512)
constexpr int OFF_H0S   = 140544;     // [256][16] u32 h0 slices
constexpr int OFF_H1S   = 144640;     // [256][16] u32 h1 slices
constexpr int OFF_HPP   = 148736;     // [256][512] f32 hidP partials
constexpr int OFF_AEH   = 279808;     // [512][256] u32 attn_W[:,512:] f16x2
constexpr int OFF_WHIDT = 410880;     // [256][512] u32 whid TRANSPOSED (kp-major)
constexpr int OFF_WIH0  = 541952;     // [1536][260] u32
constexpr int OFF_WHH0  = 941312;     // [1536][256] u32
constexpr int OFF_WIH1  = 1334528;    // [1536][256] u32
constexpr int OFF_WHH1  = 1727744;    // [1536][256] u32
constexpr int OFF_ENCP  = 2120960;    // [4096][256] u32
// end = 3169536 floats = 12.68 MB

// main-loop LDS (floats). Prologue P2 overlays [0..8192).
constexpr int L_H1   = 0;      // [256] u32 h1(t)
constexpr int L_H0   = 256;    // [256] u32 h0(t)
constexpr int L_HIDP = 512;    // [512] f32
constexpr int L_ES   = 1024;   // [16] exp(score)
constexpr int L_LL   = 1040;   // [16] L partials
constexpr int L_OUT  = 1056;   // [8]
constexpr int L_OWP  = 1064;   // [8] out weighted/xin partial
constexpr int L_HX   = 1072;   // [264] u32: xin(4)|weighted(256)|pad(4)
constexpr int L_AX   = 1336;   // [96]
constexpr int L_AH   = 1432;   // [96] ah0 fold
constexpr int L_AH1  = 1528;   // [96] ah1 fold
constexpr int L_HS   = 1624;   // [32]
constexpr int L_H1S  = 1656;   // [16] u32 packed h1new slice
constexpr int L_BIH0 = 1672, L_BHH0 = 1768, L_BIH1 = 1864, L_BHH1 = 1960;  // [96]
constexpr int L_VW   = 2056;   // [512]
constexpr int L_XIN  = 2568;   // [8]
constexpr int LDS_FLOATS = 8192;
}  // namespace

typedef _Float16 h2 __attribute__((ext_vector_type(2)));
union U32H { unsigned u; h2 h; };

__device__ __forceinline__ float dot2(unsigned a, unsigned b, float acc) {
    U32H ua, ub; ua.u = a; ub.u = b;
#if __has_builtin(__builtin_amdgcn_fdot2)
    return __builtin_amdgcn_fdot2(ua.h, ub.h, acc, false);
#else
    return acc + (float)ua.h.x * (float)ub.h.x + (float)ua.h.y * (float)ub.h.y;
#endif
}
__device__ __forceinline__ unsigned packh2(float a, float b) {
    U32H u; u.h = h2{(_Float16)a, (_Float16)b}; return u.u;
}
__device__ __forceinline__ float fsig(float x) { return 1.0f / (1.0f + __expf(-x)); }
__device__ __forceinline__ float ftanhf(float x) {
    float e = __expf(2.0f * x);
    return 1.0f - 2.0f / (e + 1.0f);
}
__device__ __forceinline__ float cload(const float* p) {
    return __hip_atomic_load(p, __ATOMIC_RELAXED, __HIP_MEMORY_SCOPE_SYSTEM);
}
__device__ __forceinline__ void cstore(float* p, float v) {
    __hip_atomic_store(p, v, __ATOMIC_RELAXED, __HIP_MEMORY_SCOPE_SYSTEM);
}
__device__ __forceinline__ unsigned ucload(const unsigned* p) {
    return __hip_atomic_load(p, __ATOMIC_RELAXED, __HIP_MEMORY_SCOPE_SYSTEM);
}
__device__ __forceinline__ void ucstore(unsigned* p, unsigned v) {
    __hip_atomic_store(p, v, __ATOMIC_RELAXED, __HIP_MEMORY_SCOPE_SYSTEM);
}

// Prologue barrier: one agent-scope wbl2 (release) / inv (acquire) per block.
__device__ __forceinline__ void bar_sync_flush(unsigned* cnt, unsigned target) {
    __syncthreads();
    if (threadIdx.x == 0) {
        __builtin_amdgcn_fence(__ATOMIC_RELEASE, "agent");
        __hip_atomic_fetch_add(cnt, 1u, __ATOMIC_RELAXED, __HIP_MEMORY_SCOPE_SYSTEM);
        while (__hip_atomic_load(cnt, __ATOMIC_RELAXED, __HIP_MEMORY_SCOPE_SYSTEM) < target)
            __builtin_amdgcn_s_sleep(8);
        __builtin_amdgcn_fence(__ATOMIC_ACQUIRE, "agent");
    }
    __syncthreads();
}

__global__ __launch_bounds__(NTHR) void decoder_kernel(
    const float* __restrict__ target, const float* __restrict__ hidden0,
    const float* __restrict__ enc, const float* __restrict__ attn_W,
    const float* __restrict__ attn_b, const float* __restrict__ v_w,
    const float* __restrict__ Wih0, const float* __restrict__ Whh0,
    const float* __restrict__ bih0, const float* __restrict__ bhh0,
    const float* __restrict__ Wih1, const float* __restrict__ Whh1,
    const float* __restrict__ bih1, const float* __restrict__ bhh1,
    const float* __restrict__ outW, const float* __restrict__ outBias,
    float* __restrict__ out, float* __restrict__ ws) {
    const int tid = threadIdx.x, bid = blockIdx.x;
    const int b = bid >> 4, s = bid & 15;

    unsigned* tags = (unsigned*)ws + OFF_TAG;
    unsigned* gridCnt = (unsigned*)ws + OFF_GRID;
    float* attP = ws + OFF_ATTP;
    unsigned* h0S = (unsigned*)(ws + OFF_H0S);
    unsigned* h1S = (unsigned*)(ws + OFF_H1S);
    float* hPP = ws + OFF_HPP;
    unsigned* aehU   = (unsigned*)(ws + OFF_AEH);
    unsigned* whidTU = (unsigned*)(ws + OFF_WHIDT);
    unsigned* wih0U = (unsigned*)(ws + OFF_WIH0);
    unsigned* whh0U = (unsigned*)(ws + OFF_WHH0);
    unsigned* wih1U = (unsigned*)(ws + OFF_WIH1);
    unsigned* whh1U = (unsigned*)(ws + OFF_WHH1);
    unsigned* encpU = (unsigned*)(ws + OFF_ENCP);

    __shared__ __align__(16) float lds[LDS_FLOATS];
    unsigned* ldsU = (unsigned*)lds;
    const int gtid = bid * NTHR + tid;

    // ===================== P1: f16 pack (plain stores) ========================
    for (int i = gtid; i < 131072; i += NBLK * NTHR) {
        const int jr = i >> 8, p = i & 255;
        aehU[i] = packh2(attn_W[jr * 1024 + 512 + 2 * p], attn_W[jr * 1024 + 513 + 2 * p]);
    }
    for (int i = gtid; i < 131072; i += NBLK * NTHR) {
        const int kp = i >> 9, r = i & 511;  // transposed: [kp][r]
        whidTU[i] = packh2(attn_W[r * 1024 + 2 * kp], attn_W[r * 1024 + 2 * kp + 1]);
    }
    for (int i = gtid; i < 399360; i += NBLK * NTHR)
        wih0U[i] = packh2(Wih0[2 * i], Wih0[2 * i + 1]);
    for (int i = gtid; i < 393216; i += NBLK * NTHR) {
        whh0U[i] = packh2(Whh0[2 * i], Whh0[2 * i + 1]);
        wih1U[i] = packh2(Wih1[2 * i], Wih1[2 * i + 1]);
        whh1U[i] = packh2(Whh1[2 * i], Whh1[2 * i + 1]);
    }
    bar_sync_flush(gridCnt, NBLK);  // one wbl2/inv per block

    // ===================== P2: enc_proj for own (b, 16 s) — self-read only ====
    {
        for (int i = 0; i < 32; ++i) {
            const int idx = tid + i * 256;
            lds[idx] = enc[(b * 256 + s * 16) * 512 + idx];  // 16 s x 512
        }
        __syncthreads();
        float a0[16], a1[16];
        const float bb0 = attn_b[2 * tid], bb1 = attn_b[2 * tid + 1];
#pragma unroll
        for (int sl = 0; sl < 16; ++sl) { a0[sl] = bb0; a1[sl] = bb1; }
        const unsigned* w0 = &aehU[(2 * tid) * 256];
        const unsigned* w1 = &aehU[(2 * tid + 1) * 256];
        for (int p = 0; p < 256; ++p) {
            const unsigned ww0 = w0[p], ww1 = w1[p];
#pragma unroll
            for (int sl = 0; sl < 16; ++sl) {
                const unsigned epk = packh2(lds[sl * 512 + 2 * p], lds[sl * 512 + 2 * p + 1]);
                a0[sl] = dot2(epk, ww0, a0[sl]);
                a1[sl] = dot2(epk, ww1, a1[sl]);
            }
        }
        for (int sl = 0; sl < 16; ++sl)  // self-read only (plain stores)
            encpU[(b * 256 + s * 16 + sl) * 256 + tid] = packh2(a0[sl], a1[sl]);
        __syncthreads();
    }

    // ===================== P3: init LDS state =================================
    if (tid < 96) {
        const int grow = (tid >> 5) * 512 + s * 32 + (tid & 31);
        lds[L_BIH0 + tid] = bih0[grow]; lds[L_BHH0 + tid] = bhh0[grow];
        lds[L_BIH1 + tid] = bih1[grow]; lds[L_BHH1 + tid] = bhh1[grow];
    }
    lds[L_VW + tid] = v_w[tid];
    lds[L_VW + 256 + tid] = v_w[256 + tid];
    ldsU[L_H0 + tid] = packh2(hidden0[b * 512 + 2 * tid], hidden0[b * 512 + 2 * tid + 1]);
    ldsU[L_H1 + tid] = packh2(hidden0[8192 + b * 512 + 2 * tid],
                              hidden0[8192 + b * 512 + 2 * tid + 1]);
    if (tid < 8) lds[L_XIN + tid] = target[b * 256 + tid];
    if (tid < 4) ldsU[L_HX + 260 + tid] = 0u;  // permanent zero tail pad
    __syncthreads();

    for (int t = 0; t < 32; ++t) {
        const unsigned tgt = (unsigned)(t + 1);

        // ---- TOP: hidP ready-up (+ out(t-1) for t>0) ----
        if (t == 0) {
            // one-time full local hidP from whidT (h1(0) local)
            float a0 = 0.f, a1 = 0.f;
            for (int kp = 0; kp < 256; ++kp) {
                const unsigned hp = ldsU[L_H1 + kp];
                a0 = dot2(whidTU[kp * 512 + tid], hp, a0);
                a1 = dot2(whidTU[kp * 512 + 256 + tid], hp, a1);
            }
            lds[L_HIDP + tid] = a0;
            lds[L_HIDP + 256 + tid] = a1;
            __syncthreads();
        } else {
            // poll tag3(t-1)==t, then gather h1(t) + sum hidP partials
            {
                const unsigned* tg = &tags[(b * 16 + (tid & 15)) * 32 + 3];
                while (ucload(tg) < (unsigned)t) __builtin_amdgcn_s_sleep(1);
            }
            __syncthreads();
            __builtin_amdgcn_fence(__ATOMIC_ACQUIRE, "workgroup");
            ldsU[L_H1 + tid] = ucload(&h1S[(b * 16 + (tid >> 4)) * 16 + (tid & 15)]);
            {
                float a0 = 0.f, a1 = 0.f;
#pragma unroll
                for (int sp = 0; sp < 16; ++sp) {
                    a0 += cload(&hPP[(b * 16 + sp) * 512 + tid]);
                    a1 += cload(&hPP[(b * 16 + sp) * 512 + 256 + tid]);
                }
                lds[L_HIDP + tid] = a0;
                lds[L_HIDP + 256 + tid] = a1;
            }
            __syncthreads();
            // out(t-1) = relu(h1part + OWP + bias)
            {
                const int f = tid >> 5, l = tid & 31;
                const float* ow = &outW[f * 1032];
                float acc = 0.f;
#pragma unroll
                for (int i = 0; i < 8; ++i) {
                    const int k2 = i * 32 + l;
                    U32H u; u.u = ldsU[L_H1 + k2];
                    acc += ow[2 * k2] * (float)u.h.x + ow[2 * k2 + 1] * (float)u.h.y;
                }
                acc += __shfl_down(acc, 16, 32); acc += __shfl_down(acc, 8, 32);
                acc += __shfl_down(acc, 4, 32); acc += __shfl_down(acc, 2, 32);
                acc += __shfl_down(acc, 1, 32);
                if (l == 0) {
                    const float o = fmaxf(acc + lds[L_OWP + f] + outBias[f], 0.f);
                    lds[L_OUT + f] = o;
                    if (s == 0) out[b * 256 + (t - 1) * 8 + f] = o;
                }
            }
            __syncthreads();
            if (tid < 8) lds[L_XIN + tid] = lds[L_OUT + tid];
            __syncthreads();
        }

        // ---- B: energy own 16 s-rows + exp + att payload -> tag1 ----
        {
            const int sloc = tid >> 4, sub = tid & 15;
            const unsigned* ep = &encpU[(b * 256 + s * 16 + sloc) * 256];
            float acc = 0.f;
#pragma unroll 4
            for (int k2 = 0; k2 < 16; ++k2) {
                const int p = k2 * 16 + sub;
                U32H u; u.u = ep[p];
                acc += lds[L_VW + 2 * p] * ftanhf((float)u.h.x + lds[L_HIDP + 2 * p]);
                acc += lds[L_VW + 2 * p + 1] * ftanhf((float)u.h.y + lds[L_HIDP + 2 * p + 1]);
            }
            acc += __shfl_down(acc, 8, 16); acc += __shfl_down(acc, 4, 16);
            acc += __shfl_down(acc, 2, 16); acc += __shfl_down(acc, 1, 16);
            if (sub == 0) lds[L_ES + sloc] = __expf(acc);  // |score|<=~20: fp32-safe
        }
        __syncthreads();
        {
            float wp0 = 0.f, wp1 = 0.f;
            const float2* er = (const float2*)&enc[(b * 256 + s * 16) * 512];
#pragma unroll
            for (int sl = 0; sl < 16; ++sl) {
                const float2 e = er[sl * 256 + tid];
                const float es = lds[L_ES + sl];
                wp0 += es * e.x; wp1 += es * e.y;
            }
            cstore(&attP[bid * 516 + 2 * tid], wp0);
            cstore(&attP[bid * 516 + 2 * tid + 1], wp1);
            if (tid == 0) {
                float l = 0.f;
#pragma unroll
                for (int i = 0; i < 16; ++i) l += lds[L_ES + i];
                cstore(&attP[bid * 516 + 512], l);
            }
        }
        __syncthreads();  // drains payload stores (all waves)
        if (tid == 0) ucstore(&tags[bid * 32 + 1], tgt);

        // ---- fold: ah0 = Whh0@h0(t) + bhh0 (local; overlaps att wait) ----
        if (tid < 192) {
            const int u = tid >> 1, sub = tid & 1;
            const int gh = u >> 5, r = u & 31;
            const int grow = gh * 512 + s * 32 + r;
            const uint4* wh = (const uint4*)&whh0U[grow * 256 + sub * 128];
            const uint4* hp = (const uint4*)&ldsU[L_H0 + sub * 128];
            float ah = 0.f;
#pragma unroll 8
            for (int k4 = 0; k4 < 32; ++k4) {
                const uint4 hv = hp[k4], wv = wh[k4];
                ah = dot2(hv.x, wv.x, ah); ah = dot2(hv.y, wv.y, ah);
                ah = dot2(hv.z, wv.z, ah); ah = dot2(hv.w, wv.w, ah);
            }
            ah += __shfl_down(ah, 1, 2);
            if (sub == 0) lds[L_AH + u] = ah + lds[L_BHH0 + u];
        }

        // ---- att sync: parallel tag polls -> gather weighted ----
        {
            const unsigned* tg = &tags[(b * 16 + (tid & 15)) * 32 + 1];
            while (ucload(tg) < tgt) __builtin_amdgcn_s_sleep(1);
        }
        __syncthreads();
        __builtin_amdgcn_fence(__ATOMIC_ACQUIRE, "workgroup");
        {
            float w0 = 0.f, w1 = 0.f;
#pragma unroll
            for (int sp = 0; sp < 16; ++sp) {
                w0 += cload(&attP[(b * 16 + sp) * 516 + 2 * tid]);
                w1 += cload(&attP[(b * 16 + sp) * 516 + 2 * tid + 1]);
            }
            if (tid < 16) lds[L_LL + tid] = cload(&attP[(b * 16 + tid) * 516 + 512]);
            __syncthreads();
            float L = 0.f;
#pragma unroll
            for (int i = 0; i < 16; ++i) L += lds[L_LL + i];
            const float inv = 1.f / L;
            ldsU[L_HX + 4 + tid] = packh2(w0 * inv, w1 * inv);
            if (tid < 4)
                ldsU[L_HX + tid] = packh2(lds[L_XIN + 2 * tid], lds[L_XIN + 2 * tid + 1]);
        }
        __syncthreads();

        // ---- C: GRU0 ax own rows + gates -> h0 slice -> tag2 ----
        if (tid < 192) {
            const int u = tid >> 1, sub = tid & 1;
            const int gh = u >> 5, r = u & 31;
            const int grow = gh * 512 + s * 32 + r;
            const uint4* wx = (const uint4*)&wih0U[grow * 260 + sub * 132];
            const uint4* xp = (const uint4*)&ldsU[L_HX + sub * 132];
            float ax = 0.f;
#pragma unroll 11
            for (int k4 = 0; k4 < 33; ++k4) {
                const uint4 xv = xp[k4], wv = wx[k4];
                ax = dot2(xv.x, wv.x, ax); ax = dot2(xv.y, wv.y, ax);
                ax = dot2(xv.z, wv.z, ax); ax = dot2(xv.w, wv.w, ax);
            }
            ax += __shfl_down(ax, 1, 2);
            if (sub == 0) lds[L_AX + u] = ax + lds[L_BIH0 + u];
        }
        __syncthreads();
        if (tid < 32) {
            const int r = tid;
            const float rg = fsig(lds[L_AX + r] + lds[L_AH + r]);
            const float z = fsig(lds[L_AX + 32 + r] + lds[L_AH + 32 + r]);
            const float n = ftanhf(lds[L_AX + 64 + r] + rg * lds[L_AH + 64 + r]);
            U32H u; u.u = ldsU[L_H0 + s * 16 + (r >> 1)];
            const float hold = (r & 1) ? (float)u.h.y : (float)u.h.x;
            const float hs = (1.f - z) * n + z * hold;
            const float hsn = __shfl_down(hs, 1, 2);
            if ((r & 1) == 0)
                ucstore(&h0S[bid * 16 + (r >> 1)], packh2(hs, hsn));
        }
        __syncthreads();  // drains slice stores
        if (tid == 0) ucstore(&tags[bid * 32 + 2], tgt);

        // ---- fold: ah1 = Whh1@h1(t) + bhh1 (local; overlaps h0 wait) ----
        if (tid < 192) {
            const int u = tid >> 1, sub = tid & 1;
            const int gh = u >> 5, r = u & 31;
            const int grow = gh * 512 + s * 32 + r;
            const uint4* wh = (const uint4*)&whh1U[grow * 256 + sub * 128];
            const uint4* hp = (const uint4*)&ldsU[L_H1 + sub * 128];
            float ah = 0.f;
#pragma unroll 8
            for (int k4 = 0; k4 < 32; ++k4) {
                const uint4 hv = hp[k4], wv = wh[k4];
                ah = dot2(hv.x, wv.x, ah); ah = dot2(hv.y, wv.y, ah);
                ah = dot2(hv.z, wv.z, ah); ah = dot2(hv.w, wv.w, ah);
            }
            ah += __shfl_down(ah, 1, 2);
            if (sub == 0) lds[L_AH1 + u] = ah + lds[L_BHH1 + u];
        }

        // ---- h0 sync: parallel polls -> gather full h0(t+1) ----
        {
            const unsigned* tg = &tags[(b * 16 + (tid & 15)) * 32 + 2];
            while (ucload(tg) < tgt) __builtin_amdgcn_s_sleep(1);
        }
        __syncthreads();
        __builtin_amdgcn_fence(__ATOMIC_ACQUIRE, "workgroup");
        ldsU[L_H0 + tid] = ucload(&h0S[(b * 16 + (tid >> 4)) * 16 + (tid & 15)]);
        __syncthreads();

        // ---- D: GRU1 ax own rows + gates -> h1 slice + hidP partials -> tag3 --
        if (tid < 192) {
            const int u = tid >> 1, sub = tid & 1;
            const int gh = u >> 5, r = u & 31;
            const int grow = gh * 512 + s * 32 + r;
            const uint4* wx = (const uint4*)&wih1U[grow * 256 + sub * 128];
            const uint4* xp = (const uint4*)&ldsU[L_H0 + sub * 128];
            float ax = 0.f;
#pragma unroll 8
            for (int k4 = 0; k4 < 32; ++k4) {
                const uint4 xv = xp[k4], wv = wx[k4];
                ax = dot2(xv.x, wv.x, ax); ax = dot2(xv.y, wv.y, ax);
                ax = dot2(xv.z, wv.z, ax); ax = dot2(xv.w, wv.w, ax);
            }
            ax += __shfl_down(ax, 1, 2);
            if (sub == 0) lds[L_AX + u] = ax + lds[L_BIH1 + u];
        }
        __syncthreads();
        if (tid < 32) {
            const int r = tid;
            const float rg = fsig(lds[L_AX + r] + lds[L_AH1 + r]);
            const float z = fsig(lds[L_AX + 32 + r] + lds[L_AH1 + 32 + r]);
            const float n = ftanhf(lds[L_AX + 64 + r] + rg * lds[L_AH1 + 64 + r]);
            U32H u; u.u = ldsU[L_H1 + s * 16 + (r >> 1)];
            const float hold = (r & 1) ? (float)u.h.y : (float)u.h.x;
            const float hs = (1.f - z) * n + z * hold;
            const float hsn = __shfl_down(hs, 1, 2);
            if ((r & 1) == 0)
                ldsU[L_H1S + (r >> 1)] = packh2(hs, hsn);
        }
        __syncthreads();
        {
            // hidP partials from own h1new slice (whidT cols s*16..s*16+15)
            float p0 = 0.f, p1 = 0.f;
#pragma unroll
            for (int k = 0; k < 16; ++k) {
                const unsigned hp = ldsU[L_H1S + k];
                p0 = dot2(whidTU[(s * 16 + k) * 512 + tid], hp, p0);
                p1 = dot2(whidTU[(s * 16 + k) * 512 + 256 + tid], hp, p1);
            }
            cstore(&hPP[bid * 512 + tid], p0);
            cstore(&hPP[bid * 512 + 256 + tid], p1);
        }
        if (tid < 16) ucstore(&h1S[bid * 16 + tid], ldsU[L_H1S + tid]);
        __syncthreads();  // drains partial + slice stores
        if (tid == 0) ucstore(&tags[bid * 32 + 3], tgt);

        // ---- fold: out weighted/xin partial (local; overlaps next-top wait) --
        {
            const int f = tid >> 5, l = tid & 31;
            const float* ow = &outW[f * 1032 + 512];
            float acc = 0.f;
#pragma unroll
            for (int i = 0; i < 8; ++i) {
                const int k2 = i * 32 + l;
                U32H u; u.u = ldsU[L_HX + 4 + k2];
                acc += ow[2 * k2] * (float)u.h.x + ow[2 * k2 + 1] * (float)u.h.y;
            }
            if (l < 8) acc += outW[f * 1032 + 1024 + l] * lds[L_XIN + l];
            acc += __shfl_down(acc, 16, 32); acc += __shfl_down(acc, 8, 32);
            acc += __shfl_down(acc, 4, 32); acc += __shfl_down(acc, 2, 32);
            acc += __shfl_down(acc, 1, 32);
            if (l == 0) lds[L_OWP + f] = acc;
        }
    }

    // ---- epilogue: out(31) ----
    {
        const unsigned* tg = &tags[(b * 16 + (tid & 15)) * 32 + 3];
        while (ucload(tg) < 32u) __builtin_amdgcn_s_sleep(1);
    }
    __syncthreads();
    __builtin_amdgcn_fence(__ATOMIC_ACQUIRE, "workgroup");
    ldsU[L_H1 + tid] = ucload(&h1S[(b * 16 + (tid >> 4)) * 16 + (tid & 15)]);
    __syncthreads();
    if (s == 0) {
        const int f = tid >> 5, l = tid & 31;
        const float* ow = &outW[f * 1032];
        float acc = 0.f;
#pragma unroll
        for (int i = 0; i < 8; ++i) {
            const int k2 = i * 32 + l;
            U32H u; u.u = ldsU[L_H1 + k2];
            acc += ow[2 * k2] * (float)u.h.x + ow[2 * k2 + 1] * (float)u.h.y;
        }
        acc += __shfl_down(acc, 16, 32); acc += __shfl_down(acc, 8, 32);
        acc += __shfl_down(acc, 4, 32); acc += __shfl_down(acc, 2, 32);
        acc += __shfl_down(acc, 1, 32);
        if (l == 0)
            out[b * 256 + 31 * 8 + f] = fmaxf(acc + lds[L_OWP + f] + outBias[f], 0.f);
    }
}

extern "C" void kernel_launch(void* const* d_in, const int* in_sizes, int n_in,
                              void* d_out, int out_size, void* d_ws, size_t ws_size,
                              hipStream_t stream) {
    (void)in_sizes; (void)n_in; (void)out_size; (void)ws_size;
    hipMemsetAsync(d_ws, 0, 36864, stream);  // tag region + grid counter
    decoder_kernel<<<NBLK, NTHR, 0, stream>>>(
        (const float*)d_in[0], (const float*)d_in[1], (const float*)d_in[2],
        (const float*)d_in[3], (const float*)d_in[4], (const float*)d_in[5],
        (const float*)d_in[6], (const float*)d_in[7], (const float*)d_in[8],
        (const float*)d_in[9], (const float*)d_in[10], (const float*)d_in[11],
        (const float*)d_in[12], (const float*)d_in[13], (const float*)d_in[14],
        (const float*)d_in[15], (float*)d_out, (float*)d_ws);
}

// Round 9
// 882.056 us; speedup vs baseline: 1.6673x; 1.6246x over previous
//
#include <hip/hip_runtime.h>

// DecoderWithAttention: B=16, T=32, F=8, S_ENC=256, H=512, L=2.
// R15 = R10 (proven 834us) with the POLL STORM removed (theory: 65k threads
// in uncached poll loops generate ~20TB/s of MALL traffic; every sync leg
// queues behind it; payload volume was shown irrelevant by R12):
//  - all 4 tag polls: tid<16 only (one thread per producer, parallel);
//    other threads park at __syncthreads. Pollers 65536 -> 4096.
//  - att partials: per-slice-normalized f16x2 (wn=wp/L_s, f16-safe) + L_s f32;
//    halves uncached store burst and gather volume.
//  - everything else byte-identical to R10 (structure, fences, layout).

namespace {
constexpr int NTHR = 256, NBLK = 256;

// ws u32/float offsets. memset covers [0, 32768) bytes.
// tags[(b*16+s)*32 + phase]; phases 0..3. grid counter at u32 8180 (phase 20
// of bid 255 -- unused phase, memset'd).
constexpr int OFF_HIDPS = 8192;       // [256][32] f32 hidP slices
constexpr int OFF_WNS   = 16384;      // [256][256] u32 normalized wp f16x2
constexpr int OFF_LS    = 81920;      // [256] f32 per-slice L
constexpr int OFF_H0S   = 82176;      // [256][16] u32 h0new slices
constexpr int OFF_H1S   = 86272;      // [256][16] u32 h1new slices
constexpr int OFF_AEH   = 90368;      // [512][256] u32 attn_W[:,512:]
constexpr int OFF_WHID  = OFF_AEH + 131072;      // [512][256] u32
constexpr int OFF_WIH0  = OFF_WHID + 131072;     // [1536][260] u32
constexpr int OFF_WHH0  = OFF_WIH0 + 399360;     // [1536][256] u32
constexpr int OFF_WIH1  = OFF_WHH0 + 393216;
constexpr int OFF_WHH1  = OFF_WIH1 + 393216;
constexpr int OFF_ENCP  = OFF_WHH1 + 393216;     // [4096][256] u32
// end = 2,980,096 floats = 11.92 MB

// LDS float/u32 offsets. P2 prologue staging uses [0..8192).
constexpr int L_H1   = 0;      // [256] u32 h1(t) f16x2 full
constexpr int L_H0   = 256;    // [256] u32 h0(t) f16x2 full
constexpr int L_HIDP = 512;    // [512] f32
constexpr int L_ES   = 1024;   // [16] exp(score) (reused for out staging)
constexpr int L_HX   = 1040;   // [264] u32: xin(4) | weighted(256) | pad(4)
constexpr int L_AX   = 1304;   // [96]
constexpr int L_AH   = 1400;   // [96]
constexpr int L_BIH0 = 1496, L_BHH0 = 1592, L_BIH1 = 1688, L_BHH1 = 1784;  // [96]
constexpr int L_VW   = 1880;   // [512]
constexpr int L_XINL = 2392;   // [8]
constexpr int L_LL   = 2400;   // [16] gathered L_s
constexpr int LDS_FLOATS = 8192;
}  // namespace

typedef _Float16 h2 __attribute__((ext_vector_type(2)));
union U32H { unsigned u; h2 h; };

__device__ __forceinline__ float dot2(unsigned a, unsigned b, float acc) {
    U32H ua, ub; ua.u = a; ub.u = b;
#if __has_builtin(__builtin_amdgcn_fdot2)
    return __builtin_amdgcn_fdot2(ua.h, ub.h, acc, false);
#else
    return acc + (float)ua.h.x * (float)ub.h.x + (float)ua.h.y * (float)ub.h.y;
#endif
}
__device__ __forceinline__ unsigned packh2(float a, float b) {
    U32H u; u.h = h2{(_Float16)a, (_Float16)b}; return u.u;
}
__device__ __forceinline__ float fsig(float x) { return 1.0f / (1.0f + __expf(-x)); }
__device__ __forceinline__ float ftanhf(float x) {
    float e = __expf(2.0f * x);
    return 1.0f - 2.0f / (e + 1.0f);
}
// Uncached per-access comm ops (sc0 sc1 -> coherence point).
__device__ __forceinline__ float cload(const float* p) {
    return __hip_atomic_load(p, __ATOMIC_RELAXED, __HIP_MEMORY_SCOPE_SYSTEM);
}
__device__ __forceinline__ void cstore(float* p, float v) {
    __hip_atomic_store(p, v, __ATOMIC_RELAXED, __HIP_MEMORY_SCOPE_SYSTEM);
}
__device__ __forceinline__ unsigned ucload(const unsigned* p) {
    return __hip_atomic_load(p, __ATOMIC_RELAXED, __HIP_MEMORY_SCOPE_SYSTEM);
}
__device__ __forceinline__ void ucstore(unsigned* p, unsigned v) {
    __hip_atomic_store(p, v, __ATOMIC_RELAXED, __HIP_MEMORY_SCOPE_SYSTEM);
}

// Prologue barrier: one agent-scope wbl2 (release) / inv (acquire) per block.
__device__ __forceinline__ void bar_sync_flush(unsigned* cnt, unsigned target) {
    __syncthreads();
    if (threadIdx.x == 0) {
        __builtin_amdgcn_fence(__ATOMIC_RELEASE, "agent");
        __hip_atomic_fetch_add(cnt, 1u, __ATOMIC_RELAXED, __HIP_MEMORY_SCOPE_SYSTEM);
        while (__hip_atomic_load(cnt, __ATOMIC_RELAXED, __HIP_MEMORY_SCOPE_SYSTEM) < target)
            __builtin_amdgcn_s_sleep(8);
        __builtin_amdgcn_fence(__ATOMIC_ACQUIRE, "agent");
    }
    __syncthreads();
}

__global__ __launch_bounds__(NTHR) void decoder_kernel(
    const float* __restrict__ target, const float* __restrict__ hidden0,
    const float* __restrict__ enc, const float* __restrict__ attn_W,
    const float* __restrict__ attn_b, const float* __restrict__ v_w,
    const float* __restrict__ Wih0, const float* __restrict__ Whh0,
    const float* __restrict__ bih0, const float* __restrict__ bhh0,
    const float* __restrict__ Wih1, const float* __restrict__ Whh1,
    const float* __restrict__ bih1, const float* __restrict__ bhh1,
    const float* __restrict__ outW, const float* __restrict__ outBias,
    float* __restrict__ out, float* __restrict__ ws) {
    const int tid = threadIdx.x, bid = blockIdx.x;
    const int b = bid >> 4, s = bid & 15;   // group (batch) / slice
    unsigned* tags = (unsigned*)ws;
    unsigned* gridCnt = (unsigned*)ws + 8180;

    float* hidPS = ws + OFF_HIDPS;
    unsigned* wnS = (unsigned*)(ws + OFF_WNS);
    float* lS = ws + OFF_LS;
    unsigned* h0S = (unsigned*)(ws + OFF_H0S);
    unsigned* h1S = (unsigned*)(ws + OFF_H1S);
    unsigned* aehU  = (unsigned*)(ws + OFF_AEH);
    unsigned* whidU = (unsigned*)(ws + OFF_WHID);
    unsigned* wih0U = (unsigned*)(ws + OFF_WIH0);
    unsigned* whh0U = (unsigned*)(ws + OFF_WHH0);
    unsigned* wih1U = (unsigned*)(ws + OFF_WIH1);
    unsigned* whh1U = (unsigned*)(ws + OFF_WHH1);
    unsigned* encpU = (unsigned*)(ws + OFF_ENCP);

    __shared__ __align__(16) float lds[LDS_FLOATS];
    unsigned* ldsU = (unsigned*)lds;
    const int gtid = bid * NTHR + tid;

    // ===================== P1: f16 pack (plain stores) ========================
    for (int i = gtid; i < 131072; i += NBLK * NTHR) {
        const int jr = i >> 8, p = i & 255;
        aehU[i]  = packh2(attn_W[jr * 1024 + 512 + 2 * p], attn_W[jr * 1024 + 513 + 2 * p]);
        whidU[i] = packh2(attn_W[jr * 1024 + 2 * p], attn_W[jr * 1024 + 1 + 2 * p]);
    }
    for (int i = gtid; i < 399360; i += NBLK * NTHR)
        wih0U[i] = packh2(Wih0[2 * i], Wih0[2 * i + 1]);
    for (int i = gtid; i < 393216; i += NBLK * NTHR) {
        whh0U[i] = packh2(Whh0[2 * i], Whh0[2 * i + 1]);
        wih1U[i] = packh2(Wih1[2 * i], Wih1[2 * i + 1]);
        whh1U[i] = packh2(Whh1[2 * i], Whh1[2 * i + 1]);
    }
    bar_sync_flush(gridCnt, NBLK);  // one wbl2/inv per block

    // ===================== P2: enc_proj for own (b, 16 s), raw f32 enc ========
    {
        for (int i = 0; i < 32; ++i) {
            const int idx = tid + i * 256;
            lds[idx] = enc[(b * 256 + s * 16) * 512 + idx];  // 16 s x 512
        }
        __syncthreads();
        float a0[16], a1[16];
        const float bb0 = attn_b[2 * tid], bb1 = attn_b[2 * tid + 1];
#pragma unroll
        for (int sl = 0; sl < 16; ++sl) { a0[sl] = bb0; a1[sl] = bb1; }
        const unsigned* w0 = &aehU[(2 * tid) * 256];
        const unsigned* w1 = &aehU[(2 * tid + 1) * 256];
        for (int p = 0; p < 256; ++p) {
            const unsigned ww0 = w0[p], ww1 = w1[p];
#pragma unroll
            for (int sl = 0; sl < 16; ++sl) {
                const unsigned epk = packh2(lds[sl * 512 + 2 * p], lds[sl * 512 + 2 * p + 1]);
                a0[sl] = dot2(epk, ww0, a0[sl]);
                a1[sl] = dot2(epk, ww1, a1[sl]);
            }
        }
        for (int sl = 0; sl < 16; ++sl)  // self-read only (plain, same-XCD L2)
            encpU[(b * 256 + s * 16 + sl) * 256 + tid] = packh2(a0[sl], a1[sl]);
        __syncthreads();
    }

    // ===================== P3: pin biases + v_w in LDS ========================
    if (tid < 96) {
        const int grow = (tid >> 5) * 512 + s * 32 + (tid & 31);
        lds[L_BIH0 + tid] = bih0[grow]; lds[L_BHH0 + tid] = bhh0[grow];
        lds[L_BIH1 + tid] = bih1[grow]; lds[L_BHH1 + tid] = bhh1[grow];
    }
    lds[L_VW + tid] = v_w[tid];
    lds[L_VW + 256 + tid] = v_w[256 + tid];
    __syncthreads();

    // initial state (t=0): h0/h1 full + x_in from target
    ldsU[L_H1 + tid] = packh2(hidden0[8192 + b * 512 + 2 * tid],
                              hidden0[8192 + b * 512 + 2 * tid + 1]);
    ldsU[L_H0 + tid] = packh2(hidden0[b * 512 + 2 * tid], hidden0[b * 512 + 2 * tid + 1]);
    if (tid < 8) lds[L_XINL + tid] = target[b * 256 + tid];
    if (tid < 4) ldsU[L_HX + 260 + tid] = 0u;  // permanent zero tail pad
    __syncthreads();

    // ===================== main recurrence (group-local, tag-polled) ==========
    for (int t = 0; t < 32; ++t) {
        const unsigned tgt = (unsigned)(t + 1);

        // ---- phase 0: hidP own rows [s*32,+32) ----
        {
            const int r = tid >> 3, sub = tid & 7;
            const uint4* wrow = (const uint4*)&whidU[(s * 32 + r) * 256 + sub * 32];
            const uint4* h1p = (const uint4*)&ldsU[L_H1 + sub * 32];
            float acc = 0.f;
#pragma unroll
            for (int k4 = 0; k4 < 8; ++k4) {
                const uint4 hv = h1p[k4], wv = wrow[k4];
                acc = dot2(hv.x, wv.x, acc); acc = dot2(hv.y, wv.y, acc);
                acc = dot2(hv.z, wv.z, acc); acc = dot2(hv.w, wv.w, acc);
            }
            acc += __shfl_down(acc, 4, 8); acc += __shfl_down(acc, 2, 8); acc += __shfl_down(acc, 1, 8);
            if (sub == 0) cstore(&hidPS[(b * 16 + s) * 32 + r], acc);
        }
        __syncthreads();                       // drains payload stores (all waves)
        if (tid == 0) ucstore(&tags[(b * 16 + s) * 32 + 0], tgt);
        if (tid < 16) {                        // 16 pollers only (poll storm fix)
            const unsigned* tg = &tags[(b * 16 + tid) * 32 + 0];
            while (ucload(tg) < tgt) __builtin_amdgcn_s_sleep(1);
        }
        __syncthreads();
        __builtin_amdgcn_fence(__ATOMIC_ACQUIRE, "workgroup");
        lds[L_HIDP + tid] = cload(&hidPS[(b * 16 + (tid >> 5)) * 32 + (tid & 31)]);
        lds[L_HIDP + 256 + tid] = cload(&hidPS[(b * 16 + 8 + (tid >> 5)) * 32 + (tid & 31)]);
        __syncthreads();

        // ---- phase 1: energy own 16 s + exp + NORMALIZED f16 wp + L ----
        {
            const int sloc = tid >> 4, sub = tid & 15;
            const unsigned* ep = &encpU[(b * 256 + s * 16 + sloc) * 256];
            float acc = 0.f;
#pragma unroll 4
            for (int k2 = 0; k2 < 16; ++k2) {
                const int p = k2 * 16 + sub;
                U32H u; u.u = ep[p];
                acc += lds[L_VW + 2 * p] * ftanhf((float)u.h.x + lds[L_HIDP + 2 * p]);
                acc += lds[L_VW + 2 * p + 1] * ftanhf((float)u.h.y + lds[L_HIDP + 2 * p + 1]);
            }
            acc += __shfl_down(acc, 8, 16); acc += __shfl_down(acc, 4, 16);
            acc += __shfl_down(acc, 2, 16); acc += __shfl_down(acc, 1, 16);
            if (sub == 0) lds[L_ES + sloc] = __expf(acc);  // |score|<=~20: fp32-safe
        }
        __syncthreads();
        {
            float l = 0.f;
#pragma unroll
            for (int i = 0; i < 16; ++i) l += lds[L_ES + i];
            const float invl = 1.f / l;
            float wp0 = 0.f, wp1 = 0.f;
            const float2* er = (const float2*)&enc[(b * 256 + s * 16) * 512];
#pragma unroll
            for (int sl = 0; sl < 16; ++sl) {
                const float2 e = er[sl * 256 + tid];
                const float es = lds[L_ES + sl];
                wp0 += es * e.x; wp1 += es * e.y;
            }
            // per-slice normalized: |wn| <= max|enc| -> f16-safe
            ucstore(&wnS[(b * 16 + s) * 256 + tid], packh2(wp0 * invl, wp1 * invl));
            if (tid == 0) cstore(&lS[b * 16 + s], l);
        }
        __syncthreads();
        if (tid == 0) ucstore(&tags[(b * 16 + s) * 32 + 1], tgt);
        if (tid < 16) {
            const unsigned* tg = &tags[(b * 16 + tid) * 32 + 1];
            while (ucload(tg) < tgt) __builtin_amdgcn_s_sleep(1);
            lds[L_LL + tid] = cload(&lS[b * 16 + tid]);  // own producer's L
        }
        __syncthreads();
        __builtin_amdgcn_fence(__ATOMIC_ACQUIRE, "workgroup");
        {
            float Lsum = 0.f;
#pragma unroll
            for (int i = 0; i < 16; ++i) Lsum += lds[L_LL + i];
            const float inv = 1.f / Lsum;
            float w0 = 0.f, w1 = 0.f;
#pragma unroll
            for (int sp = 0; sp < 16; ++sp) {
                U32H u; u.u = ucload(&wnS[(b * 16 + sp) * 256 + tid]);
                const float Ls = lds[L_LL + sp];
                w0 += Ls * (float)u.h.x; w1 += Ls * (float)u.h.y;
            }
            ldsU[L_HX + 4 + tid] = packh2(w0 * inv, w1 * inv);
            if (tid < 4)
                ldsU[L_HX + tid] = packh2(lds[L_XINL + 2 * tid], lds[L_XINL + 2 * tid + 1]);
        }
        __syncthreads();

        // ---- phase 2: GRU0 gate rows [s*32,+32) -> h0new slice ----
        if (tid < 192) {
            const int u = tid >> 1, sub = tid & 1;
            const int gh = u >> 5, r = u & 31;
            const int grow = gh * 512 + s * 32 + r;
            const uint4* wx = (const uint4*)&wih0U[grow * 260 + sub * 132];
            const uint4* xp = (const uint4*)&ldsU[L_HX + sub * 132];
            float ax = 0.f;
#pragma unroll 11
            for (int k4 = 0; k4 < 33; ++k4) {
                const uint4 xv = xp[k4], wv = wx[k4];
                ax = dot2(xv.x, wv.x, ax); ax = dot2(xv.y, wv.y, ax);
                ax = dot2(xv.z, wv.z, ax); ax = dot2(xv.w, wv.w, ax);
            }
            const uint4* wh = (const uint4*)&whh0U[grow * 256 + sub * 128];
            const uint4* hp = (const uint4*)&ldsU[L_H0 + sub * 128];
            float ah = 0.f;
#pragma unroll 8
            for (int k4 = 0; k4 < 32; ++k4) {
                const uint4 hv = hp[k4], wv = wh[k4];
                ah = dot2(hv.x, wv.x, ah); ah = dot2(hv.y, wv.y, ah);
                ah = dot2(hv.z, wv.z, ah); ah = dot2(hv.w, wv.w, ah);
            }
            ax += __shfl_down(ax, 1, 2); ah += __shfl_down(ah, 1, 2);
            if (sub == 0) {
                lds[L_AX + u] = ax + lds[L_BIH0 + u];
                lds[L_AH + u] = ah + lds[L_BHH0 + u];
            }
        }
        __syncthreads();
        if (tid < 32) {
            const int r = tid;
            const float rg = fsig(lds[L_AX + r] + lds[L_AH + r]);
            const float z = fsig(lds[L_AX + 32 + r] + lds[L_AH + 32 + r]);
            const float n = ftanhf(lds[L_AX + 64 + r] + rg * lds[L_AH + 64 + r]);
            U32H u; u.u = ldsU[L_H0 + s * 16 + (r >> 1)];
            const float hold = (r & 1) ? (float)u.h.y : (float)u.h.x;
            const float hs = (1.f - z) * n + z * hold;
            const float hsn = __shfl_down(hs, 1, 2);
            if ((r & 1) == 0)
                ucstore(&h0S[(b * 16 + s) * 16 + (r >> 1)], packh2(hs, hsn));
        }
        __syncthreads();
        if (tid == 0) ucstore(&tags[(b * 16 + s) * 32 + 2], tgt);
        if (tid < 16) {
            const unsigned* tg = &tags[(b * 16 + tid) * 32 + 2];
            while (ucload(tg) < tgt) __builtin_amdgcn_s_sleep(1);
        }
        __syncthreads();
        __builtin_amdgcn_fence(__ATOMIC_ACQUIRE, "workgroup");
        ldsU[L_H0 + tid] = ucload(&h0S[(b * 16 + (tid >> 4)) * 16 + (tid & 15)]);
        __syncthreads();

        // ---- phase 3: GRU1 gate rows [s*32,+32) -> h1new slice ----
        if (tid < 192) {
            const int u = tid >> 1, sub = tid & 1;
            const int gh = u >> 5, r = u & 31;
            const int grow = gh * 512 + s * 32 + r;
            const uint4* wx = (const uint4*)&wih1U[grow * 256 + sub * 128];
            const uint4* xp = (const uint4*)&ldsU[L_H0 + sub * 128];
            float ax = 0.f;
#pragma unroll 8
            for (int k4 = 0; k4 < 32; ++k4) {
                const uint4 xv = xp[k4], wv = wx[k4];
                ax = dot2(xv.x, wv.x, ax); ax = dot2(xv.y, wv.y, ax);
                ax = dot2(xv.z, wv.z, ax); ax = dot2(xv.w, wv.w, ax);
            }
            const uint4* wh = (const uint4*)&whh1U[grow * 256 + sub * 128];
            const uint4* hp = (const uint4*)&ldsU[L_H1 + sub * 128];
            float ah = 0.f;
#pragma unroll 8
            for (int k4 = 0; k4 < 32; ++k4) {
                const uint4 hv = hp[k4], wv = wh[k4];
                ah = dot2(hv.x, wv.x, ah); ah = dot2(hv.y, wv.y, ah);
                ah = dot2(hv.z, wv.z, ah); ah = dot2(hv.w, wv.w, ah);
            }
            ax += __shfl_down(ax, 1, 2); ah += __shfl_down(ah, 1, 2);
            if (sub == 0) {
                lds[L_AX + u] = ax + lds[L_BIH1 + u];
                lds[L_AH + u] = ah + lds[L_BHH1 + u];
            }
        }
        __syncthreads();
        if (tid < 32) {
            const int r = tid;
            const float rg = fsig(lds[L_AX + r] + lds[L_AH + r]);
            const float z = fsig(lds[L_AX + 32 + r] + lds[L_AH + 32 + r]);
            const float n = ftanhf(lds[L_AX + 64 + r] + rg * lds[L_AH + 64 + r]);
            U32H u; u.u = ldsU[L_H1 + s * 16 + (r >> 1)];
            const float hold = (r & 1) ? (float)u.h.y : (float)u.h.x;
            const float hs = (1.f - z) * n + z * hold;
            const float hsn = __shfl_down(hs, 1, 2);
            if ((r & 1) == 0)
                ucstore(&h1S[(b * 16 + s) * 16 + (r >> 1)], packh2(hs, hsn));
        }
        __syncthreads();
        if (tid == 0) ucstore(&tags[(b * 16 + s) * 32 + 3], tgt);
        if (tid < 16) {
            const unsigned* tg = &tags[(b * 16 + tid) * 32 + 3];
            while (ucload(tg) < tgt) __builtin_amdgcn_s_sleep(1);
        }
        __syncthreads();
        __builtin_amdgcn_fence(__ATOMIC_ACQUIRE, "workgroup");
        ldsU[L_H1 + tid] = ucload(&h1S[(b * 16 + (tid >> 4)) * 16 + (tid & 15)]);
        __syncthreads();

        // ---- phase 4 (local): out = relu(outW.[h1new|weighted|xin]+b) --------
        {
            const int f = tid >> 5, l = tid & 31;
            const float* ow = &outW[f * 1032];
            float acc = 0.f;
#pragma unroll
            for (int i = 0; i < 8; ++i) {
                const int k2 = i * 32 + l;
                U32H u; u.u = ldsU[L_H1 + k2];
                acc += ow[2 * k2] * (float)u.h.x + ow[2 * k2 + 1] * (float)u.h.y;
            }
#pragma unroll
            for (int i = 0; i < 8; ++i) {
                const int k2 = i * 32 + l;
                U32H u; u.u = ldsU[L_HX + 4 + k2];
                acc += ow[512 + 2 * k2] * (float)u.h.x + ow[512 + 2 * k2 + 1] * (float)u.h.y;
            }
            if (l < 8) acc += ow[1024 + l] * lds[L_XINL + l];
            acc += __shfl_down(acc, 16, 32); acc += __shfl_down(acc, 8, 32);
            acc += __shfl_down(acc, 4, 32); acc += __shfl_down(acc, 2, 32);
            acc += __shfl_down(acc, 1, 32);
            if (l == 0) {
                const float o = fmaxf(acc + outBias[f], 0.f);
                lds[L_ES + f] = o;
                if (s == 0) out[b * 256 + t * 8 + f] = o;
            }
        }
        __syncthreads();
        if (tid < 8) lds[L_XINL + tid] = lds[L_ES + tid];
        __syncthreads();
    }
}

extern "C" void kernel_launch(void* const* d_in, const int* in_sizes, int n_in,
                              void* d_out, int out_size, void* d_ws, size_t ws_size,
                              hipStream_t stream) {
    (void)in_sizes; (void)n_in; (void)out_size; (void)ws_size;
    hipMemsetAsync(d_ws, 0, 32768, stream);  // zero tag region + grid counter
    decoder_kernel<<<NBLK, NTHR, 0, stream>>>(
        (const float*)d_in[0], (const float*)d_in[1], (const float*)d_in[2],
        (const float*)d_in[3], (const float*)d_in[4], (const float*)d_in[5],
        (const float*)d_in[6], (const float*)d_in[7], (const float*)d_in[8],
        (const float*)d_in[9], (const float*)d_in[10], (const float*)d_in[11],
        (const float*)d_in[12], (const float*)d_in[13], (const float*)d_in[14],
        (const float*)d_in[15], (float*)d_out, (float*)d_ws);
}